// Round 9
// baseline (6149.018 us; speedup 1.0000x reference)
//
#include <hip/hip_runtime.h>
#include <hip/hip_fp16.h>

typedef _Float16 f16;
typedef _Float16 f16x8 __attribute__((ext_vector_type(8)));
typedef float f32x4 __attribute__((ext_vector_type(4)));

#define B_ 1024
#define T_ 128
#define F_ 9
#define H_ 256
#define P_ 2048

// ---------------- helpers ----------------
__device__ __forceinline__ float sigf(float x) { return 1.f / (1.f + __expf(-x)); }
__device__ __forceinline__ float tanh_(float x) {
  float a = fminf(fabsf(x), 12.f);
  float e = __expf(2.f * a);
  float r = 1.f - 2.f / (e + 1.f);
  return copysignf(r, x);
}

__device__ __forceinline__ float blk_sum(float v) {
  __shared__ float sh[8];
  int lane = threadIdx.x & 63, w = threadIdx.x >> 6;
  int nw = blockDim.x >> 6;
#pragma unroll
  for (int o = 32; o > 0; o >>= 1) v += __shfl_xor(v, o, 64);
  __syncthreads();
  if (lane == 0) sh[w] = v;
  __syncthreads();
  float t = 0.f;
  for (int i = 0; i < nw; i++) t += sh[i];
  return t;
}

// ---------------- generic fp16 MFMA GEMM ----------------
__global__ __launch_bounds__(256) void gemm_f16(
    const f16* __restrict__ A, int lda,
    const f16* __restrict__ Bt, int ldb,
    const float* __restrict__ bias,
    f16* __restrict__ o16, int ldo16,
    float* __restrict__ o32, int ldo32,
    int M, int N, int K)
{
  __shared__ __align__(16) f16 As[128][40];
  __shared__ __align__(16) f16 Bs[128][40];
  const int tid = threadIdx.x;
  const int lane = tid & 63, wave = tid >> 6;
  const int wr = (wave >> 1) * 64, wc = (wave & 1) * 64;
  const int q = lane >> 4, l15 = lane & 15;
  const int bm = blockIdx.x * 128, bn = blockIdx.y * 128;

  f32x4 acc[4][4];
#pragma unroll
  for (int i = 0; i < 4; i++)
#pragma unroll
    for (int j = 0; j < 4; j++) acc[i][j] = (f32x4){0.f, 0.f, 0.f, 0.f};

  for (int k0 = 0; k0 < K; k0 += 32) {
#pragma unroll
    for (int c = 0; c < 2; ++c) {
      int ch = tid + c * 256;
      int row = ch >> 2, kh = (ch & 3) * 8;
      *(f16x8*)&As[row][kh] = *(const f16x8*)&A[(size_t)(bm + row) * lda + k0 + kh];
      *(f16x8*)&Bs[row][kh] = *(const f16x8*)&Bt[(size_t)(bn + row) * ldb + k0 + kh];
    }
    __syncthreads();
    f16x8 af[4], bf[4];
#pragma unroll
    for (int tm = 0; tm < 4; tm++) af[tm] = *(const f16x8*)&As[wr + tm * 16 + l15][q * 8];
#pragma unroll
    for (int tn = 0; tn < 4; tn++) bf[tn] = *(const f16x8*)&Bs[wc + tn * 16 + l15][q * 8];
#pragma unroll
    for (int tm = 0; tm < 4; tm++)
#pragma unroll
      for (int tn = 0; tn < 4; tn++)
        acc[tm][tn] = __builtin_amdgcn_mfma_f32_16x16x32_f16(af[tm], bf[tn], acc[tm][tn], 0, 0, 0);
    __syncthreads();
  }
#pragma unroll
  for (int tm = 0; tm < 4; tm++) {
#pragma unroll
    for (int tn = 0; tn < 4; tn++) {
      int colg = bn + wc + tn * 16 + l15;
      float bv = bias ? bias[colg] : 0.f;
#pragma unroll
      for (int r = 0; r < 4; r++) {
        int rowg = bm + wr + tm * 16 + q * 4 + r;
        float v = acc[tm][tn][r] + bv;
        if (o32) o32[(size_t)rowg * ldo32 + colg] = v;
        if (o16) o16[(size_t)rowg * ldo16 + colg] = (f16)v;
      }
    }
  }
}

// ---------------- LSTM scan: Whh-only, single block per 16 rows --------------
// grid CR/16 x 256 threads (4 waves, 1 wave/SIMD -> 512 regs/lane).
// xp (CR,T,1024) f16 = x@Wih^T + bias (chunk-local rows). Wave w owns out-cols
// [w*64, w*64+64) of all 4 gates. Gates i,f,g Whh weights (384 regs/lane)
// live in registers the whole scan; gate-o streamed from L2 per step (same
// 128 KB every step -> L2-hot, overlapped with MFMAs). h-state in LDS
// fragments; xp staged to LDS for next step. NO inter-block communication.
__global__ __launch_bounds__(256, 1) void lstm_scan(
    const f16* __restrict__ xp,    // chunk-local (CR,T,1024)
    f16* __restrict__ hs,          // chunk-offset (CR,T,256) out
    const f16* __restrict__ wpkR,  // [w4][g3][ct4][k8][lane64][8]
    const f16* __restrict__ wpkL)  // [w4][ct4][k8][lane64][8]  (gate o)
{
  __shared__ __align__(16) f16 aph[8][64][8];     // h fragments, 8 KB
  __shared__ __align__(16) f16 xps[16 * 1032];    // xp staging, 33 KB (padded)
  const int tid = threadIdx.x;
  const int lane = tid & 63, w = tid >> 6;
  const int q = lane >> 4, l15 = lane & 15;
  const int m0 = blockIdx.x * 16;

  // 3 register gates: 96 x f16x8 per lane
  f16x8 bf[3][4][8];
  {
    const f16* wr = wpkR + (size_t)w * 49152 + (size_t)lane * 8;
#pragma unroll
    for (int g = 0; g < 3; g++)
#pragma unroll
      for (int ct = 0; ct < 4; ct++)
#pragma unroll
        for (int k = 0; k < 8; k++)
          bf[g][ct][k] = *(const f16x8*)(wr + (size_t)((g * 4 + ct) * 8 + k) * 512);
  }
  const f16* wl = wpkL + (size_t)w * 16384 + (size_t)lane * 8;

  // zero h fragments (512 f16x8 slots, 2 per thread)
#pragma unroll
  for (int c = 0; c < 2; c++) {
    int sl = tid + c * 256;
    *(f16x8*)&aph[sl >> 6][sl & 63][0] = (f16x8){};
  }
  // stage xp(t=0): 2048 chunks of 8 f16, 8 per thread
#pragma unroll
  for (int c = 0; c < 8; c++) {
    int ch = tid + c * 256;
    int row = ch >> 7, jc = (ch & 127) * 8;
    *(f16x8*)&xps[row * 1032 + jc] =
        *(const f16x8*)&xp[((size_t)(m0 + row) * T_) * 1024 + jc];
  }
  float cst[4][4];
#pragma unroll
  for (int ct = 0; ct < 4; ct++)
#pragma unroll
    for (int r = 0; r < 4; r++) cst[ct][r] = 0.f;
  __syncthreads();   // S1(0): aph + xps ready

  for (int t = 0; t < T_; ++t) {
    f16 hn[4][4];
#pragma unroll
    for (int ct = 0; ct < 4; ct++) {
      // gate-o B-frags streamed from L2 (same addrs every step -> L2-hot)
      f16x8 b3[8];
#pragma unroll
      for (int k = 0; k < 8; k++)
        b3[k] = *(const f16x8*)(wl + (size_t)(ct * 8 + k) * 512);
      f32x4 acc0 = {0.f,0.f,0.f,0.f}, acc1 = acc0, acc2 = acc0, acc3 = acc0;
#pragma unroll
      for (int k = 0; k < 8; k++) {
        f16x8 a = *(const f16x8*)&aph[k][lane][0];
        acc0 = __builtin_amdgcn_mfma_f32_16x16x32_f16(a, bf[0][ct][k], acc0, 0, 0, 0);
        acc1 = __builtin_amdgcn_mfma_f32_16x16x32_f16(a, bf[1][ct][k], acc1, 0, 0, 0);
        acc2 = __builtin_amdgcn_mfma_f32_16x16x32_f16(a, bf[2][ct][k], acc2, 0, 0, 0);
        acc3 = __builtin_amdgcn_mfma_f32_16x16x32_f16(a, b3[k], acc3, 0, 0, 0);
      }
      int colL = w * 64 + ct * 16 + l15;
#pragma unroll
      for (int r = 0; r < 4; r++) {
        int row = q * 4 + r;
        float ip = acc0[r] + (float)xps[row * 1032 + colL];
        float fp = acc1[r] + (float)xps[row * 1032 + 256 + colL];
        float gp = acc2[r] + (float)xps[row * 1032 + 512 + colL];
        float op = acc3[r] + (float)xps[row * 1032 + 768 + colL];
        float cn = sigf(fp) * cst[ct][r] + sigf(ip) * tanh_(gp);
        cst[ct][r] = cn;
        hn[ct][r] = (f16)(sigf(op) * tanh_(cn));
      }
    }
    __syncthreads();   // S2: all aph/xps reads of step t done
    // write h_t: LDS fragments (next step's A) + global hs (fire-forget)
#pragma unroll
    for (int ct = 0; ct < 4; ct++) {
      int col = w * 64 + ct * 16 + l15;
      int kh = col >> 5, ph = ((col >> 3) & 3) * 16, jh = col & 7;
#pragma unroll
      for (int r = 0; r < 4; r++) {
        int row = q * 4 + r;
        aph[kh][ph + row][jh] = hn[ct][r];
        hs[((size_t)(m0 + row) * T_ + t) * 256 + col] = hn[ct][r];
      }
    }
    // stage xp(t+1)
    if (t + 1 < T_) {
#pragma unroll
      for (int c = 0; c < 8; c++) {
        int ch = tid + c * 256;
        int row = ch >> 7, jc = (ch & 127) * 8;
        *(f16x8*)&xps[row * 1032 + jc] =
            *(const f16x8*)&xp[((size_t)(m0 + row) * T_ + t + 1) * 1024 + jc];
      }
    }
    __syncthreads();   // S1(t+1)
  }
}

// ---------------- VSN phase 1: softmax weights ----------------
__global__ __launch_bounds__(256) void vsn_w_kernel(
    const float* __restrict__ x, const float* __restrict__ selw,
    const float* __restrict__ selb, float* __restrict__ wb)
{
  int pos = blockIdx.x * 256 + threadIdx.x;
  const float* xr = x + (size_t)pos * F_;
  float xv[F_];
#pragma unroll
  for (int f = 0; f < F_; f++) xv[f] = xr[f];
  float wv[F_]; float mx = -1e30f;
#pragma unroll
  for (int f = 0; f < F_; f++) {
    float s = selb[f];
#pragma unroll
    for (int f2 = 0; f2 < F_; f2++) s += xv[f2] * selw[f * F_ + f2];
    wv[f] = s; mx = fmaxf(mx, s);
  }
  float se = 0.f;
#pragma unroll
  for (int f = 0; f < F_; f++) { wv[f] = __expf(wv[f] - mx); se += wv[f]; }
  float inv = 1.f / se;
  float* o = wb + (size_t)pos * 18;
#pragma unroll
  for (int f = 0; f < F_; f++) {
    float wt = wv[f] * inv;
    o[f] = wt; o[9 + f] = wt * xv[f];
  }
}

// ---------------- EW/EB: fold Wih0 through the VSN basis ----------------
// EW[f][j] = embw[f,:]·Wih0[j,:]; EB[f][j] = embb[f,:]·Wih0[j,:]
__global__ __launch_bounds__(256) void ew_kernel(
    const float* __restrict__ embw, const float* __restrict__ embb,
    const float* __restrict__ Wih0, float* __restrict__ EW, float* __restrict__ EB)
{
  int idx = blockIdx.x * 256 + threadIdx.x;   // 36 blocks, 9216 = 9*1024
  int f = idx >> 10, j = idx & 1023;
  const float* er = embw + f * H_;
  const float* br = embb + f * H_;
  const float* wr = Wih0 + (size_t)j * H_;
  float ew = 0.f, eb = 0.f;
  for (int k = 0; k < H_; k++) { ew += er[k] * wr[k]; eb += br[k] * wr[k]; }
  EW[idx] = ew; EB[idx] = eb;
}

// ---------------- xp0 chunk = VSN folded through Wih0, bias added ----------------
// grid (CR, 4): block handles one batch row (128 t) x 256 cols.
__global__ __launch_bounds__(256) void vsn_xp_kernel(
    const float* __restrict__ wb, const float* __restrict__ EW,
    const float* __restrict__ EB, const float* __restrict__ bias0,
    f16* __restrict__ xp, int r0)
{
  int col = blockIdx.y * 256 + threadIdx.x;
  float ew[F_], eb[F_];
#pragma unroll
  for (int f = 0; f < F_; f++) { ew[f] = EW[f * 1024 + col]; eb[f] = EB[f * 1024 + col]; }
  float b0 = bias0[col];
  int rl = blockIdx.x;
  for (int t = 0; t < T_; t++) {
    const float* wv = wb + ((size_t)(r0 + rl) * T_ + t) * 18;
    float v = b0;
#pragma unroll
    for (int f = 0; f < F_; f++) v += wv[9 + f] * ew[f] + wv[f] * eb[f];
    xp[((size_t)rl * T_ + t) * 1024 + col] = (f16)v;
  }
}

// ---------------- attention in h-space ----------------
__global__ __launch_bounds__(256) void qk_kernel(
    const float* __restrict__ qbuf, const float* __restrict__ attn_in_w,
    float* __restrict__ qk)
{
  __shared__ float qs[256];
  int b = blockIdx.x, j = threadIdx.x;
  qs[j] = qbuf[(size_t)b * 256 + j];
  __syncthreads();
#pragma unroll
  for (int h = 0; h < 4; h++) {
    float acc = 0.f;
    for (int d = 0; d < 64; d++)
      acc += qs[h * 64 + d] * attn_in_w[(size_t)(256 + h * 64 + d) * 256 + j];
    qk[((size_t)b * 4 + h) * 256 + j] = acc * 0.125f;
  }
}

__global__ __launch_bounds__(256) void attnpool_kernel(
    const f16* __restrict__ hseq, const float* __restrict__ qk,
    float* __restrict__ hbar)
{
  __shared__ __align__(16) f16 hsb[T_][264];
  __shared__ float qks[4][256];
  __shared__ float ps[4][T_];
  int b = blockIdx.x, tid = threadIdx.x;
  for (int i = tid; i < T_ * 32; i += 256) {
    int row = i >> 5, cc = (i & 31) * 8;
    *(f16x8*)&hsb[row][cc] = *(const f16x8*)&hseq[((size_t)b * T_ + row) * 256 + cc];
  }
  for (int i = tid; i < 1024; i += 256) qks[i >> 8][i & 255] = qk[(size_t)b * 1024 + i];
  __syncthreads();
  if (tid < T_) {
    float s[4] = {0.f, 0.f, 0.f, 0.f};
    for (int cc = 0; cc < 32; cc++) {
      f16x8 v = *(const f16x8*)&hsb[tid][cc * 8];
#pragma unroll
      for (int h = 0; h < 4; h++) {
        float a = 0.f;
#pragma unroll
        for (int j = 0; j < 8; j++) a += qks[h][cc * 8 + j] * (float)v[j];
        s[h] += a;
      }
    }
#pragma unroll
    for (int h = 0; h < 4; h++) ps[h][tid] = s[h];
  }
  __syncthreads();
  {
    int w = tid >> 6, l = tid & 63;
    float a = ps[w][l], bb = ps[w][l + 64];
    float m = fmaxf(a, bb);
#pragma unroll
    for (int o = 32; o > 0; o >>= 1) m = fmaxf(m, __shfl_xor(m, o, 64));
    float e0 = __expf(a - m), e1 = __expf(bb - m);
    float se = e0 + e1;
#pragma unroll
    for (int o = 32; o > 0; o >>= 1) se += __shfl_xor(se, o, 64);
    float inv = 1.f / se;
    ps[w][l] = e0 * inv; ps[w][l + 64] = e1 * inv;
  }
  __syncthreads();
  int j = tid;
  float acc[4] = {0.f, 0.f, 0.f, 0.f};
  for (int t = 0; t < T_; t++) {
    float hv = (float)hsb[t][j];
#pragma unroll
    for (int h = 0; h < 4; h++) acc[h] += ps[h][t] * hv;
  }
#pragma unroll
  for (int h = 0; h < 4; h++) hbar[((size_t)b * 4 + h) * 256 + j] = acc[h];
}

__global__ __launch_bounds__(256) void vproj_kernel(
    const float* __restrict__ hbar, const float* __restrict__ attn_in_w,
    const float* __restrict__ attn_in_b, f16* __restrict__ aob)
{
  __shared__ float hb[4][256];
  int b = blockIdx.x, tid = threadIdx.x;
  for (int i = tid; i < 1024; i += 256) hb[i >> 8][i & 255] = hbar[(size_t)b * 1024 + i];
  __syncthreads();
  int d = tid, h = d >> 6;
  const float4* wr = (const float4*)(attn_in_w + (size_t)(512 + d) * 256);
  float acc = 0.f;
  for (int cc = 0; cc < 64; cc++) {
    float4 w4 = wr[cc];
    acc += w4.x * hb[h][cc * 4] + w4.y * hb[h][cc * 4 + 1]
         + w4.z * hb[h][cc * 4 + 2] + w4.w * hb[h][cc * 4 + 3];
  }
  aob[(size_t)b * 256 + d] = (f16)(acc + attn_in_b[512 + d]);
}

// ---------------- GNN prep ----------------
__global__ __launch_bounds__(256) void deg_adjn_kernel(
    const float* __restrict__ adj, const int* __restrict__ sku,
    f16* __restrict__ adjn)
{
  int bp = blockIdx.x;
  int p = sku[bp];
  int tid = threadIdx.x;
  float s = 0.f;
  for (int j = tid; j < P_; j += 256) s += adj[(size_t)p * P_ + j];
  float tot = blk_sum(s);
  float inv = 1.f / fmaxf(tot, 1e-6f);
  for (int b = tid; b < B_; b += 256)
    adjn[(size_t)bp * B_ + b] = (f16)(adj[(size_t)p * P_ + sku[b]] * inv);
}

__global__ void transpose_kernel(const float* __restrict__ hid, f16* __restrict__ hT)
{
  int i = blockIdx.x * 256 + threadIdx.x;
  int b = i >> 8, j = i & 255;
  hT[(size_t)j * B_ + b] = (f16)hid[i];
}

__global__ __launch_bounds__(256) void gelu_ln_kernel(
    const float* __restrict__ pre, const float* __restrict__ lg,
    const float* __restrict__ lb, float* __restrict__ enr,
    f16* __restrict__ hidcat)
{
  int row = blockIdx.x, j = threadIdx.x;
  float xv = pre[row * 256 + j];
  float ge = 0.5f * xv * (1.f + erff(xv * 0.70710678118654752f));
  float mu = blk_sum(ge) * (1.f / 256.f);
  float d = ge - mu;
  float var = blk_sum(d * d) * (1.f / 256.f);
  float y = d * rsqrtf(var + 1e-5f) * lg[j] + lb[j];
  enr[row * 256 + j] = y;
  hidcat[row * 512 + 256 + j] = (f16)y;
}

__global__ __launch_bounds__(256) void final_kernel(
    const float* __restrict__ gpre, const float* __restrict__ enr,
    const float* __restrict__ hid, const float* __restrict__ outw,
    const float* __restrict__ outb, float* __restrict__ out)
{
  int b = blockIdx.x, j = threadIdx.x;
  float gt = sigf(gpre[b * 256 + j]);
  float comb = gt * enr[b * 256 + j] + (1.f - gt) * hid[b * 256 + j];
  float v = comb * outw[j];
  float s = blk_sum(v);
  if (j == 0) out[b] = s + outb[0];
}

// ---------------- one-shot weight prep ----------------
// Whh pack (per layer, 262144 elems): R-part (i<196608): [w4][g3][ct4][k8][lane64][j8]
//   row = g*256 + w*64 + ct*16 + (lane&15), col = k*32 + (lane>>4)*8 + j
// L-part (gate o): [w4][ct4][k8][lane64][j8], row = 768 + w*64 + ct*16 + (lane&15)
// Segments: 524288 + 262144 + 65536*3 + 131072 + 2*1024 = 1116160 = 4360 blocks.
__global__ void prep_kernel(
    const float* Whh0, const float* Whh1, const float* Wih1,
    const float* bih0, const float* bhh0, const float* bih1, const float* bhh1,
    const float* attn_in_w, const float* attn_out_w, const float* gnn_w,
    const float* gate_w,
    f16* wpkR0, f16* wpkL0, f16* wpkR1, f16* wpkL1, f16* wih1f,
    f16* attninf, f16* attnoutf, f16* gnnwf, f16* gatewf,
    float* bias0, float* bias1)
{
  int idx = blockIdx.x * 256 + threadIdx.x;
  if (idx < 524288) {
    int l = idx >> 18;
    int i = idx & 262143;
    const float* Whh = l ? Whh1 : Whh0;
    if (i < 196608) {
      int w = i / 49152, r1 = i % 49152;
      int g = r1 / 16384, r2 = r1 % 16384;
      int ct = r2 >> 12, k = (r2 >> 9) & 7, lane = (r2 >> 3) & 63, j = r2 & 7;
      int row = g * 256 + w * 64 + ct * 16 + (lane & 15);
      int col = k * 32 + (lane >> 4) * 8 + j;
      (l ? wpkR1 : wpkR0)[i] = (f16)Whh[(size_t)row * 256 + col];
    } else {
      int iL = i - 196608;
      int w = iL >> 14, ct = (iL >> 12) & 3, k = (iL >> 9) & 7;
      int lane = (iL >> 3) & 63, j = iL & 7;
      int row = 768 + w * 64 + ct * 16 + (lane & 15);
      int col = k * 32 + (lane >> 4) * 8 + j;
      (l ? wpkL1 : wpkL0)[iL] = (f16)Whh[(size_t)row * 256 + col];
    }
    return;
  }
  int i = idx - 524288;
  if (i < 262144) { wih1f[i] = (f16)Wih1[i]; return; }
  i -= 262144;
  if (i < 65536) { attninf[i] = (f16)attn_in_w[i]; return; }
  i -= 65536;
  if (i < 65536) { attnoutf[i] = (f16)attn_out_w[i]; return; }
  i -= 65536;
  if (i < 65536) { gnnwf[i] = (f16)gnn_w[i]; return; }
  i -= 65536;
  if (i < 131072) { gatewf[i] = (f16)gate_w[i]; return; }
  i -= 131072;
  if (i < 1024) { bias0[i] = bih0[i] + bhh0[i]; return; }
  i -= 1024;
  if (i < 1024) { bias1[i] = bih1[i] + bhh1[i]; return; }
}

// ---------------- launch ----------------
extern "C" void kernel_launch(void* const* d_in, const int* in_sizes, int n_in,
                              void* d_out, int out_size, void* d_ws, size_t ws_size,
                              hipStream_t stream)
{
  const float* x         = (const float*)d_in[0];
  const int*   sku       = (const int*)  d_in[1];
  const float* adj       = (const float*)d_in[2];
  const float* vsn_emb_w = (const float*)d_in[3];
  const float* vsn_emb_b = (const float*)d_in[4];
  const float* vsn_sel_w = (const float*)d_in[5];
  const float* vsn_sel_b = (const float*)d_in[6];
  const float* Wih0 = (const float*)d_in[7];
  const float* Whh0 = (const float*)d_in[8];
  const float* bih0 = (const float*)d_in[9];
  const float* bhh0 = (const float*)d_in[10];
  const float* Wih1 = (const float*)d_in[11];
  const float* Whh1 = (const float*)d_in[12];
  const float* bih1 = (const float*)d_in[13];
  const float* bhh1 = (const float*)d_in[14];
  const float* attn_in_w  = (const float*)d_in[15];
  const float* attn_in_b  = (const float*)d_in[16];
  const float* attn_out_w = (const float*)d_in[17];
  const float* attn_out_b = (const float*)d_in[18];
  const float* gnn_w  = (const float*)d_in[19];
  const float* gnn_b  = (const float*)d_in[20];
  const float* ln_g   = (const float*)d_in[21];
  const float* ln_b   = (const float*)d_in[22];
  const float* gate_w = (const float*)d_in[23];
  const float* gate_b = (const float*)d_in[24];
  const float* out_w  = (const float*)d_in[25];
  const float* out_b  = (const float*)d_in[26];
  (void)in_sizes; (void)n_in; (void)out_size;

  char* wsb = (char*)d_ws;
  size_t off = 0;
  auto alloc = [&](size_t bytes) -> void* {
    void* p = wsb + off;
    off += (bytes + 255) & ~(size_t)255;
    return p;
  };
  // persistent region
  f16* hsbuf   = (f16*)alloc((size_t)B_ * T_ * H_ * 2);    // 67 MB
  f16* wpkR0   = (f16*)alloc((size_t)196608 * 2);
  f16* wpkL0   = (f16*)alloc((size_t)65536 * 2);
  f16* wpkR1   = (f16*)alloc((size_t)196608 * 2);
  f16* wpkL1   = (f16*)alloc((size_t)65536 * 2);
  f16* wih1f   = (f16*)alloc((size_t)262144 * 2);
  f16* attninf = (f16*)alloc((size_t)65536 * 2);
  f16* attnoutf= (f16*)alloc((size_t)65536 * 2);
  f16* gnnwf   = (f16*)alloc((size_t)65536 * 2);
  f16* gatewf  = (f16*)alloc((size_t)131072 * 2);
  float* bias0 = (float*)alloc(1024 * 4);
  float* bias1 = (float*)alloc(1024 * 4);
  float* EW    = (float*)alloc(9216 * 4);
  float* EB    = (float*)alloc(9216 * 4);
  // wb (9.44 MB): live only until the last layer-0 vsn_xp chunk
  float* wb    = (float*)alloc((size_t)B_ * T_ * 18 * 4);
  size_t off_xp = off;                        // xp chunk lives here
  // tail buffers: used only AFTER both scans -> alias wb + xp head
  size_t off2 = (size_t)((char*)wb - wsb);
  auto alloc2 = [&](size_t bytes) -> void* {
    void* p = wsb + off2;
    off2 += (bytes + 255) & ~(size_t)255;
    return p;
  };
  float* qbuf  = (float*)alloc2((size_t)B_ * 256 * 4);
  float* qk    = (float*)alloc2((size_t)B_ * 4 * 256 * 4);
  float* hbar  = (float*)alloc2((size_t)B_ * 4 * 256 * 4);
  f16* aob     = (f16*)alloc2((size_t)B_ * 256 * 2);
  float* hidden32 = (float*)alloc2((size_t)B_ * 256 * 4);
  f16* hidcat  = (f16*)alloc2((size_t)B_ * 512 * 2);
  f16* hT      = (f16*)alloc2((size_t)256 * B_ * 2);
  f16* adjn    = (f16*)alloc2((size_t)B_ * B_ * 2);
  f16* aggf    = (f16*)alloc2((size_t)B_ * 256 * 2);
  float* gnnpre= (float*)alloc2((size_t)B_ * 256 * 4);
  float* enr32 = (float*)alloc2((size_t)B_ * 256 * 4);
  float* gatepre=(float*)alloc2((size_t)B_ * 256 * 4);

  // pick the largest xp chunk that fits ws_size (deterministic per session)
  const size_t xp_full = (size_t)B_ * T_ * 1024 * 2;   // 268 MB
  int nch = 32;
  for (int n = 1; n <= 32; n <<= 1)
    if (off_xp + xp_full / (size_t)n <= ws_size) { nch = n; break; }
  const int CR = B_ / nch;                   // rows per chunk (>= 32)
  f16* xpch = (f16*)(wsb + off_xp);
  // ensure tail fits too (it overlaps wb+xp head; xp chunk >= 8.4 MB ok)

  prep_kernel<<<4360, 256, 0, stream>>>(
      Whh0, Whh1, Wih1, bih0, bhh0, bih1, bhh1,
      attn_in_w, attn_out_w, gnn_w, gate_w,
      wpkR0, wpkL0, wpkR1, wpkL1, wih1f,
      attninf, attnoutf, gnnwf, gatewf, bias0, bias1);
  ew_kernel<<<36, 256, 0, stream>>>(vsn_emb_w, vsn_emb_b, Wih0, EW, EB);
  vsn_w_kernel<<<512, 256, 0, stream>>>(x, vsn_sel_w, vsn_sel_b, wb);

  // LSTM layer 0: per chunk, xp0 (Wih0 folded through VSN) -> Whh-only scan
  for (int c = 0; c < nch; ++c) {
    int r0 = c * CR;
    vsn_xp_kernel<<<dim3(CR, 4), 256, 0, stream>>>(wb, EW, EB, bias0, xpch, r0);
    lstm_scan<<<CR / 16, 256, 0, stream>>>(xpch, hsbuf + (size_t)r0 * T_ * 256,
                                           wpkR0, wpkL0);
  }
  // LSTM layer 1: per chunk, xp1 GEMM -> scan (hs overwritten in place)
  for (int c = 0; c < nch; ++c) {
    int r0 = c * CR;
    gemm_f16<<<dim3(CR * T_ / 128, 8), 256, 0, stream>>>(
        hsbuf + (size_t)r0 * T_ * 256, 256, wih1f, 256, bias1,
        xpch, 1024, nullptr, 0, CR * T_, 1024, 256);
    lstm_scan<<<CR / 16, 256, 0, stream>>>(xpch, hsbuf + (size_t)r0 * T_ * 256,
                                           wpkR1, wpkL1);
  }

  // q at t=T-1
  dim3 gS(B_ / 128, 256 / 128);
  gemm_f16<<<gS, 256, 0, stream>>>(hsbuf + (size_t)(T_ - 1) * 256, T_ * 256, attninf, 256,
                                   attn_in_b, nullptr, 0, qbuf, 256, B_, 256, 256);
  // attention folded into h-space
  qk_kernel<<<B_, 256, 0, stream>>>(qbuf, attn_in_w, qk);
  attnpool_kernel<<<B_, 256, 0, stream>>>(hsbuf, qk, hbar);
  vproj_kernel<<<B_, 256, 0, stream>>>(hbar, attn_in_w, attn_in_b, aob);
  // hidden
  gemm_f16<<<gS, 256, 0, stream>>>(aob, 256, attnoutf, 256, attn_out_b,
                                   hidcat, 512, hidden32, 256, B_, 256, 256);
  // GNN
  deg_adjn_kernel<<<B_, 256, 0, stream>>>(adj, sku, adjn);
  transpose_kernel<<<B_, 256, 0, stream>>>(hidden32, hT);
  gemm_f16<<<gS, 256, 0, stream>>>(adjn, 1024, hT, 1024, nullptr,
                                   aggf, 256, nullptr, 0, B_, 256, 1024);
  gemm_f16<<<gS, 256, 0, stream>>>(aggf, 256, gnnwf, 256, gnn_b,
                                   nullptr, 0, gnnpre, 256, B_, 256, 256);
  gelu_ln_kernel<<<B_, 256, 0, stream>>>(gnnpre, ln_g, ln_b, enr32, hidcat);
  // gate + output
  gemm_f16<<<gS, 256, 0, stream>>>(hidcat, 512, gatewf, 512, gate_b,
                                   nullptr, 0, gatepre, 256, B_, 256, 512);
  final_kernel<<<B_, 256, 0, stream>>>(gatepre, enr32, hidden32, out_w, out_b, (float*)d_out);
}

// Round 10
// 3431.999 us; speedup vs baseline: 1.7917x; 1.7917x over previous
//
#include <hip/hip_runtime.h>
#include <hip/hip_fp16.h>

typedef _Float16 f16;
typedef _Float16 f16x8 __attribute__((ext_vector_type(8)));
typedef float f32x4 __attribute__((ext_vector_type(4)));

#define B_ 1024
#define T_ 128
#define F_ 9
#define H_ 256
#define P_ 2048
#define TW_ 64   // time window

// ---------------- helpers ----------------
__device__ __forceinline__ float sigf(float x) { return 1.f / (1.f + __expf(-x)); }
__device__ __forceinline__ float tanh_(float x) {
  float a = fminf(fabsf(x), 12.f);
  float e = __expf(2.f * a);
  float r = 1.f - 2.f / (e + 1.f);
  return copysignf(r, x);
}

__device__ __forceinline__ float blk_sum(float v) {
  __shared__ float sh[8];
  int lane = threadIdx.x & 63, w = threadIdx.x >> 6;
  int nw = blockDim.x >> 6;
#pragma unroll
  for (int o = 32; o > 0; o >>= 1) v += __shfl_xor(v, o, 64);
  __syncthreads();
  if (lane == 0) sh[w] = v;
  __syncthreads();
  float t = 0.f;
  for (int i = 0; i < nw; i++) t += sh[i];
  return t;
}

// ---------------- generic fp16 MFMA GEMM (segmented A rows) ----------------
// A row r lives at A + (r>>seg_shift)*seg_stride + (r&mask)*lda.
// Plain layout: seg_shift=30, seg_stride=0.
__global__ __launch_bounds__(256) void gemm_f16(
    const f16* __restrict__ A, int lda, int seg_shift, size_t seg_stride,
    const f16* __restrict__ Bt, int ldb,
    const float* __restrict__ bias,
    f16* __restrict__ o16, int ldo16,
    float* __restrict__ o32, int ldo32,
    int M, int N, int K)
{
  __shared__ __align__(16) f16 As[128][40];
  __shared__ __align__(16) f16 Bs[128][40];
  const int tid = threadIdx.x;
  const int lane = tid & 63, wave = tid >> 6;
  const int wr = (wave >> 1) * 64, wc = (wave & 1) * 64;
  const int q = lane >> 4, l15 = lane & 15;
  const int bm = blockIdx.x * 128, bn = blockIdx.y * 128;
  const int smask = (1 << seg_shift) - 1;

  f32x4 acc[4][4];
#pragma unroll
  for (int i = 0; i < 4; i++)
#pragma unroll
    for (int j = 0; j < 4; j++) acc[i][j] = (f32x4){0.f, 0.f, 0.f, 0.f};

  for (int k0 = 0; k0 < K; k0 += 32) {
#pragma unroll
    for (int c = 0; c < 2; ++c) {
      int ch = tid + c * 256;
      int row = ch >> 2, kh = (ch & 3) * 8;
      int r = bm + row;
      const f16* arow = A + (size_t)(r >> seg_shift) * seg_stride
                          + (size_t)(r & smask) * lda;
      *(f16x8*)&As[row][kh] = *(const f16x8*)&arow[k0 + kh];
      *(f16x8*)&Bs[row][kh] = *(const f16x8*)&Bt[(size_t)(bn + row) * ldb + k0 + kh];
    }
    __syncthreads();
    f16x8 af[4], bf[4];
#pragma unroll
    for (int tm = 0; tm < 4; tm++) af[tm] = *(const f16x8*)&As[wr + tm * 16 + l15][q * 8];
#pragma unroll
    for (int tn = 0; tn < 4; tn++) bf[tn] = *(const f16x8*)&Bs[wc + tn * 16 + l15][q * 8];
#pragma unroll
    for (int tm = 0; tm < 4; tm++)
#pragma unroll
      for (int tn = 0; tn < 4; tn++)
        acc[tm][tn] = __builtin_amdgcn_mfma_f32_16x16x32_f16(af[tm], bf[tn], acc[tm][tn], 0, 0, 0);
    __syncthreads();
  }
#pragma unroll
  for (int tm = 0; tm < 4; tm++) {
#pragma unroll
    for (int tn = 0; tn < 4; tn++) {
      int colg = bn + wc + tn * 16 + l15;
      float bv = bias ? bias[colg] : 0.f;
#pragma unroll
      for (int r = 0; r < 4; r++) {
        int rowg = bm + wr + tm * 16 + q * 4 + r;
        float v = acc[tm][tn][r] + bv;
        if (o32) o32[(size_t)rowg * ldo32 + colg] = v;
        if (o16) o16[(size_t)rowg * ldo16 + colg] = (f16)v;
      }
    }
  }
}

// ---------------- LSTM scan: T-windowed, 2 reg gates + 2 streamed --------------
// grid 64 x 256 (4 waves, 1 wave/SIMD -> 512 regs/lane). Window [t0, t0+64).
// xp (B, TW_, 1024): x-projection incl bias, window-local time index.
// Wave w owns out-cols [w*64,w*64+64) of each gate. Gates i,f in registers
// (256 regs, no spill); gates g,o streamed from L2 per ct (addresses repeat
// every step -> L2-hot; latency hidden by MFMA+VALU of the step).
// Double-buffered LDS (aph, xps) -> ONE barrier per step. xp(t+1) prefetched
// into registers at step top. c-state crosses windows via cbuf; h via hs.
__global__ __launch_bounds__(256, 1) void lstm_scan(
    const f16* __restrict__ xp,
    f16* __restrict__ hs,          // (B, T_, 256)
    const f16* __restrict__ wpkR,  // [w4][g2][ct4][k8][lane64][8]  gates i,f
    const f16* __restrict__ wpkL,  // [w4][g2][ct4][k8][lane64][8]  gates g,o
    float* __restrict__ cbuf,      // 64*256*16 f32
    int t0)
{
  __shared__ __align__(16) f16 aph[2][8][64][8];   // 16 KB
  __shared__ __align__(16) f16 xps[2][16 * 1032];  // 66 KB
  const int tid = threadIdx.x;
  const int lane = tid & 63, w = tid >> 6;
  const int q = lane >> 4, l15 = lane & 15;
  const int m0 = blockIdx.x * 16;

  // register gates i,f: 64 x f16x8 = 256 regs/lane
  f16x8 bf[2][4][8];
  {
    const f16* wr = wpkR + (size_t)w * 32768 + (size_t)lane * 8;
#pragma unroll
    for (int g = 0; g < 2; g++)
#pragma unroll
      for (int ct = 0; ct < 4; ct++)
#pragma unroll
        for (int k = 0; k < 8; k++)
          bf[g][ct][k] = *(const f16x8*)(wr + (size_t)((g * 4 + ct) * 8 + k) * 512);
  }
  const f16* wl = wpkL + (size_t)w * 32768 + (size_t)lane * 8;

  // init h fragments (zero at t0==0, else reload h[t0-1] from hs)
#pragma unroll
  for (int c = 0; c < 2; c++) {
    int sl = tid + c * 256, k = sl >> 6, ls = sl & 63;
    f16x8 h0 = {};
    if (t0 > 0)
      h0 = *(const f16x8*)&hs[((size_t)(m0 + (ls & 15)) * T_ + t0 - 1) * 256
                              + k * 32 + (ls >> 4) * 8];
    *(f16x8*)&aph[0][k][ls][0] = h0;
  }
  // init c-state
  float cst[4][4];
  float* cslot = cbuf + ((size_t)blockIdx.x * 256 + tid) * 16;
#pragma unroll
  for (int i = 0; i < 16; i++) cst[i >> 2][i & 3] = 0.f;
  if (t0 > 0)
#pragma unroll
    for (int i = 0; i < 16; i++) cst[i >> 2][i & 3] = cslot[i];
  // stage xp(tw=0)
#pragma unroll
  for (int c = 0; c < 8; c++) {
    int ch = tid + c * 256, row = ch >> 7, jc = (ch & 127) * 8;
    *(f16x8*)&xps[0][row * 1032 + jc] =
        *(const f16x8*)&xp[((size_t)(m0 + row) * TW_) * 1024 + jc];
  }
  __syncthreads();

  for (int tw = 0; tw < TW_; ++tw) {
    const int p = tw & 1;
    // prefetch xp(tw+1) into regs -- latency overlapped by the whole step
    f16x8 xr2[8];
    if (tw + 1 < TW_) {
#pragma unroll
      for (int c = 0; c < 8; c++) {
        int ch = tid + c * 256, row = ch >> 7, jc = (ch & 127) * 8;
        xr2[c] = *(const f16x8*)&xp[((size_t)(m0 + row) * TW_ + tw + 1) * 1024 + jc];
      }
    }
    f16 hn[4][4];
#pragma unroll
    for (int ct = 0; ct < 4; ct++) {
      f16x8 bs2[8], bs3[8];   // streamed gates g,o (L2-hot)
#pragma unroll
      for (int k = 0; k < 8; k++) {
        bs2[k] = *(const f16x8*)(wl + (size_t)((0 * 4 + ct) * 8 + k) * 512);
        bs3[k] = *(const f16x8*)(wl + (size_t)((1 * 4 + ct) * 8 + k) * 512);
      }
      f32x4 a0 = {0.f,0.f,0.f,0.f}, a1 = a0, a2 = a0, a3 = a0;
#pragma unroll
      for (int k = 0; k < 8; k++) {
        f16x8 a = *(const f16x8*)&aph[p][k][lane][0];
        a0 = __builtin_amdgcn_mfma_f32_16x16x32_f16(a, bf[0][ct][k], a0, 0, 0, 0);
        a1 = __builtin_amdgcn_mfma_f32_16x16x32_f16(a, bf[1][ct][k], a1, 0, 0, 0);
        a2 = __builtin_amdgcn_mfma_f32_16x16x32_f16(a, bs2[k], a2, 0, 0, 0);
        a3 = __builtin_amdgcn_mfma_f32_16x16x32_f16(a, bs3[k], a3, 0, 0, 0);
      }
      int colL = w * 64 + ct * 16 + l15;
#pragma unroll
      for (int r = 0; r < 4; r++) {
        int row = q * 4 + r;
        float ip = a0[r] + (float)xps[p][row * 1032 + colL];
        float fp = a1[r] + (float)xps[p][row * 1032 + 256 + colL];
        float gp = a2[r] + (float)xps[p][row * 1032 + 512 + colL];
        float op = a3[r] + (float)xps[p][row * 1032 + 768 + colL];
        float cn = sigf(fp) * cst[ct][r] + sigf(ip) * tanh_(gp);
        cst[ct][r] = cn;
        hn[ct][r] = (f16)(sigf(op) * tanh_(cn));
      }
    }
    // write h_t into the OTHER buffers (p^1) + global hs; stage xp(tw+1)
#pragma unroll
    for (int ct = 0; ct < 4; ct++) {
      int col = w * 64 + ct * 16 + l15;
      int kh = col >> 5, ph = ((col >> 3) & 3) * 16, jh = col & 7;
#pragma unroll
      for (int r = 0; r < 4; r++) {
        int row = q * 4 + r;
        aph[p ^ 1][kh][ph + row][jh] = hn[ct][r];
        hs[((size_t)(m0 + row) * T_ + t0 + tw) * 256 + col] = hn[ct][r];
      }
    }
    if (tw + 1 < TW_) {
#pragma unroll
      for (int c = 0; c < 8; c++) {
        int ch = tid + c * 256, row = ch >> 7, jc = (ch & 127) * 8;
        *(f16x8*)&xps[p ^ 1][row * 1032 + jc] = xr2[c];
      }
    }
    __syncthreads();   // single barrier/step (double-buffered LDS)
  }
#pragma unroll
  for (int i = 0; i < 16; i++) cslot[i] = cst[i >> 2][i & 3];
}

// ---------------- VSN phase 1: softmax weights ----------------
__global__ __launch_bounds__(256) void vsn_w_kernel(
    const float* __restrict__ x, const float* __restrict__ selw,
    const float* __restrict__ selb, float* __restrict__ wb)
{
  int pos = blockIdx.x * 256 + threadIdx.x;
  const float* xr = x + (size_t)pos * F_;
  float xv[F_];
#pragma unroll
  for (int f = 0; f < F_; f++) xv[f] = xr[f];
  float wv[F_]; float mx = -1e30f;
#pragma unroll
  for (int f = 0; f < F_; f++) {
    float s = selb[f];
#pragma unroll
    for (int f2 = 0; f2 < F_; f2++) s += xv[f2] * selw[f * F_ + f2];
    wv[f] = s; mx = fmaxf(mx, s);
  }
  float se = 0.f;
#pragma unroll
  for (int f = 0; f < F_; f++) { wv[f] = __expf(wv[f] - mx); se += wv[f]; }
  float inv = 1.f / se;
  float* o = wb + (size_t)pos * 18;
#pragma unroll
  for (int f = 0; f < F_; f++) {
    float wt = wv[f] * inv;
    o[f] = wt; o[9 + f] = wt * xv[f];
  }
}

// ---------------- EW/EB: fold Wih0 through the VSN basis ----------------
__global__ __launch_bounds__(256) void ew_kernel(
    const float* __restrict__ embw, const float* __restrict__ embb,
    const float* __restrict__ Wih0, float* __restrict__ EW, float* __restrict__ EB)
{
  int idx = blockIdx.x * 256 + threadIdx.x;   // 36 blocks
  int f = idx >> 10, j = idx & 1023;
  const float* er = embw + f * H_;
  const float* br = embb + f * H_;
  const float* wr = Wih0 + (size_t)j * H_;
  float ew = 0.f, eb = 0.f;
  for (int k = 0; k < H_; k++) { ew += er[k] * wr[k]; eb += br[k] * wr[k]; }
  EW[idx] = ew; EB[idx] = eb;
}

// ---------------- xp0 window = VSN folded through Wih0 ----------------
__global__ __launch_bounds__(256) void vsn_xp_kernel(
    const float* __restrict__ wb, const float* __restrict__ EW,
    const float* __restrict__ EB, const float* __restrict__ bias0,
    f16* __restrict__ xp, int t0)
{
  int col = blockIdx.y * 256 + threadIdx.x;
  float ew[F_], eb[F_];
#pragma unroll
  for (int f = 0; f < F_; f++) { ew[f] = EW[f * 1024 + col]; eb[f] = EB[f * 1024 + col]; }
  float b0 = bias0[col];
  int r = blockIdx.x;
  for (int t = 0; t < TW_; t++) {
    const float* wv = wb + ((size_t)r * T_ + t0 + t) * 18;
    float v = b0;
#pragma unroll
    for (int f = 0; f < F_; f++) v += wv[9 + f] * ew[f] + wv[f] * eb[f];
    xp[((size_t)r * TW_ + t) * 1024 + col] = (f16)v;
  }
}

// ---------------- attention in h-space ----------------
__global__ __launch_bounds__(256) void qk_kernel(
    const float* __restrict__ qbuf, const float* __restrict__ attn_in_w,
    float* __restrict__ qk)
{
  __shared__ float qs[256];
  int b = blockIdx.x, j = threadIdx.x;
  qs[j] = qbuf[(size_t)b * 256 + j];
  __syncthreads();
#pragma unroll
  for (int h = 0; h < 4; h++) {
    float acc = 0.f;
    for (int d = 0; d < 64; d++)
      acc += qs[h * 64 + d] * attn_in_w[(size_t)(256 + h * 64 + d) * 256 + j];
    qk[((size_t)b * 4 + h) * 256 + j] = acc * 0.125f;
  }
}

__global__ __launch_bounds__(256) void attnpool_kernel(
    const f16* __restrict__ hseq, const float* __restrict__ qk,
    float* __restrict__ hbar)
{
  __shared__ __align__(16) f16 hsb[T_][264];
  __shared__ float qks[4][256];
  __shared__ float ps[4][T_];
  int b = blockIdx.x, tid = threadIdx.x;
  for (int i = tid; i < T_ * 32; i += 256) {
    int row = i >> 5, cc = (i & 31) * 8;
    *(f16x8*)&hsb[row][cc] = *(const f16x8*)&hseq[((size_t)b * T_ + row) * 256 + cc];
  }
  for (int i = tid; i < 1024; i += 256) qks[i >> 8][i & 255] = qk[(size_t)b * 1024 + i];
  __syncthreads();
  if (tid < T_) {
    float s[4] = {0.f, 0.f, 0.f, 0.f};
    for (int cc = 0; cc < 32; cc++) {
      f16x8 v = *(const f16x8*)&hsb[tid][cc * 8];
#pragma unroll
      for (int h = 0; h < 4; h++) {
        float a = 0.f;
#pragma unroll
        for (int j = 0; j < 8; j++) a += qks[h][cc * 8 + j] * (float)v[j];
        s[h] += a;
      }
    }
#pragma unroll
    for (int h = 0; h < 4; h++) ps[h][tid] = s[h];
  }
  __syncthreads();
  {
    int w = tid >> 6, l = tid & 63;
    float a = ps[w][l], bb = ps[w][l + 64];
    float m = fmaxf(a, bb);
#pragma unroll
    for (int o = 32; o > 0; o >>= 1) m = fmaxf(m, __shfl_xor(m, o, 64));
    float e0 = __expf(a - m), e1 = __expf(bb - m);
    float se = e0 + e1;
#pragma unroll
    for (int o = 32; o > 0; o >>= 1) se += __shfl_xor(se, o, 64);
    float inv = 1.f / se;
    ps[w][l] = e0 * inv; ps[w][l + 64] = e1 * inv;
  }
  __syncthreads();
  int j = tid;
  float acc[4] = {0.f, 0.f, 0.f, 0.f};
  for (int t = 0; t < T_; t++) {
    float hv = (float)hsb[t][j];
#pragma unroll
    for (int h = 0; h < 4; h++) acc[h] += ps[h][t] * hv;
  }
#pragma unroll
  for (int h = 0; h < 4; h++) hbar[((size_t)b * 4 + h) * 256 + j] = acc[h];
}

__global__ __launch_bounds__(256) void vproj_kernel(
    const float* __restrict__ hbar, const float* __restrict__ attn_in_w,
    const float* __restrict__ attn_in_b, f16* __restrict__ aob)
{
  __shared__ float hb[4][256];
  int b = blockIdx.x, tid = threadIdx.x;
  for (int i = tid; i < 1024; i += 256) hb[i >> 8][i & 255] = hbar[(size_t)b * 1024 + i];
  __syncthreads();
  int d = tid, h = d >> 6;
  const float4* wr = (const float4*)(attn_in_w + (size_t)(512 + d) * 256);
  float acc = 0.f;
  for (int cc = 0; cc < 64; cc++) {
    float4 w4 = wr[cc];
    acc += w4.x * hb[h][cc * 4] + w4.y * hb[h][cc * 4 + 1]
         + w4.z * hb[h][cc * 4 + 2] + w4.w * hb[h][cc * 4 + 3];
  }
  aob[(size_t)b * 256 + d] = (f16)(acc + attn_in_b[512 + d]);
}

// ---------------- GNN prep ----------------
__global__ __launch_bounds__(256) void deg_adjn_kernel(
    const float* __restrict__ adj, const int* __restrict__ sku,
    f16* __restrict__ adjn)
{
  int bp = blockIdx.x;
  int p = sku[bp];
  int tid = threadIdx.x;
  float s = 0.f;
  for (int j = tid; j < P_; j += 256) s += adj[(size_t)p * P_ + j];
  float tot = blk_sum(s);
  float inv = 1.f / fmaxf(tot, 1e-6f);
  for (int b = tid; b < B_; b += 256)
    adjn[(size_t)bp * B_ + b] = (f16)(adj[(size_t)p * P_ + sku[b]] * inv);
}

__global__ void transpose_kernel(const float* __restrict__ hid, f16* __restrict__ hT)
{
  int i = blockIdx.x * 256 + threadIdx.x;
  int b = i >> 8, j = i & 255;
  hT[(size_t)j * B_ + b] = (f16)hid[i];
}

__global__ __launch_bounds__(256) void gelu_ln_kernel(
    const float* __restrict__ pre, const float* __restrict__ lg,
    const float* __restrict__ lb, float* __restrict__ enr,
    f16* __restrict__ hidcat)
{
  int row = blockIdx.x, j = threadIdx.x;
  float xv = pre[row * 256 + j];
  float ge = 0.5f * xv * (1.f + erff(xv * 0.70710678118654752f));
  float mu = blk_sum(ge) * (1.f / 256.f);
  float d = ge - mu;
  float var = blk_sum(d * d) * (1.f / 256.f);
  float y = d * rsqrtf(var + 1e-5f) * lg[j] + lb[j];
  enr[row * 256 + j] = y;
  hidcat[row * 512 + 256 + j] = (f16)y;
}

__global__ __launch_bounds__(256) void final_kernel(
    const float* __restrict__ gpre, const float* __restrict__ enr,
    const float* __restrict__ hid, const float* __restrict__ outw,
    const float* __restrict__ outb, float* __restrict__ out)
{
  int b = blockIdx.x, j = threadIdx.x;
  float gt = sigf(gpre[b * 256 + j]);
  float comb = gt * enr[b * 256 + j] + (1.f - gt) * hid[b * 256 + j];
  float v = comb * outw[j];
  float s = blk_sum(v);
  if (j == 0) out[b] = s + outb[0];
}

// ---------------- one-shot weight prep ----------------
// Whh pack per layer (262144): R half (gates i,f): [w4][g2][ct4][k8][lane64][j8]
//   row = g*256 + w*64 + ct*16 + (lane&15); col = k*32 + (lane>>4)*8 + j
// L half (gates g,o): same layout, row = (2+g)*256 + w*64 + ct*16 + (lane&15)
// Segments: 524288 + 262144 + 65536*3 + 131072 + 2*1024 = 1116160 = 4360 blocks.
__global__ void prep_kernel(
    const float* Whh0, const float* Whh1, const float* Wih1,
    const float* bih0, const float* bhh0, const float* bih1, const float* bhh1,
    const float* attn_in_w, const float* attn_out_w, const float* gnn_w,
    const float* gate_w,
    f16* wpkR0, f16* wpkL0, f16* wpkR1, f16* wpkL1, f16* wih1f,
    f16* attninf, f16* attnoutf, f16* gnnwf, f16* gatewf,
    float* bias0, float* bias1)
{
  int idx = blockIdx.x * 256 + threadIdx.x;
  if (idx < 524288) {
    int l = idx >> 18;
    int i = idx & 262143;
    const float* Whh = l ? Whh1 : Whh0;
    int half = (i >= 131072);
    int ih = i & 131071;
    int w = ih >> 15, r1 = ih & 32767;
    int g = r1 >> 14, r2 = r1 & 16383;
    int ct = r2 >> 12, k = (r2 >> 9) & 7, lane = (r2 >> 3) & 63, j = r2 & 7;
    int row = (half * 2 + g) * 256 + w * 64 + ct * 16 + (lane & 15);
    int col = k * 32 + (lane >> 4) * 8 + j;
    f16 v = (f16)Whh[(size_t)row * 256 + col];
    if (l) { if (half) wpkL1[ih] = v; else wpkR1[ih] = v; }
    else   { if (half) wpkL0[ih] = v; else wpkR0[ih] = v; }
    return;
  }
  int i = idx - 524288;
  if (i < 262144) { wih1f[i] = (f16)Wih1[i]; return; }
  i -= 262144;
  if (i < 65536) { attninf[i] = (f16)attn_in_w[i]; return; }
  i -= 65536;
  if (i < 65536) { attnoutf[i] = (f16)attn_out_w[i]; return; }
  i -= 65536;
  if (i < 65536) { gnnwf[i] = (f16)gnn_w[i]; return; }
  i -= 65536;
  if (i < 131072) { gatewf[i] = (f16)gate_w[i]; return; }
  i -= 131072;
  if (i < 1024) { bias0[i] = bih0[i] + bhh0[i]; return; }
  i -= 1024;
  if (i < 1024) { bias1[i] = bih1[i] + bhh1[i]; return; }
}

// ---------------- launch ----------------
extern "C" void kernel_launch(void* const* d_in, const int* in_sizes, int n_in,
                              void* d_out, int out_size, void* d_ws, size_t ws_size,
                              hipStream_t stream)
{
  const float* x         = (const float*)d_in[0];
  const int*   sku       = (const int*)  d_in[1];
  const float* adj       = (const float*)d_in[2];
  const float* vsn_emb_w = (const float*)d_in[3];
  const float* vsn_emb_b = (const float*)d_in[4];
  const float* vsn_sel_w = (const float*)d_in[5];
  const float* vsn_sel_b = (const float*)d_in[6];
  const float* Wih0 = (const float*)d_in[7];
  const float* Whh0 = (const float*)d_in[8];
  const float* bih0 = (const float*)d_in[9];
  const float* bhh0 = (const float*)d_in[10];
  const float* Wih1 = (const float*)d_in[11];
  const float* Whh1 = (const float*)d_in[12];
  const float* bih1 = (const float*)d_in[13];
  const float* bhh1 = (const float*)d_in[14];
  const float* attn_in_w  = (const float*)d_in[15];
  const float* attn_in_b  = (const float*)d_in[16];
  const float* attn_out_w = (const float*)d_in[17];
  const float* attn_out_b = (const float*)d_in[18];
  const float* gnn_w  = (const float*)d_in[19];
  const float* gnn_b  = (const float*)d_in[20];
  const float* ln_g   = (const float*)d_in[21];
  const float* ln_b   = (const float*)d_in[22];
  const float* gate_w = (const float*)d_in[23];
  const float* gate_b = (const float*)d_in[24];
  const float* out_w  = (const float*)d_in[25];
  const float* out_b  = (const float*)d_in[26];
  (void)in_sizes; (void)n_in; (void)out_size; (void)ws_size;

  char* wsb = (char*)d_ws;
  size_t off = 0;
  auto alloc = [&](size_t bytes) -> void* {
    void* p = wsb + off;
    off += (bytes + 255) & ~(size_t)255;
    return p;
  };
  // persistent region (~80 MB)
  f16* hsbuf   = (f16*)alloc((size_t)B_ * T_ * H_ * 2);    // 67 MB
  f16* wpkR0   = (f16*)alloc((size_t)131072 * 2);
  f16* wpkL0   = (f16*)alloc((size_t)131072 * 2);
  f16* wpkR1   = (f16*)alloc((size_t)131072 * 2);
  f16* wpkL1   = (f16*)alloc((size_t)131072 * 2);
  f16* wih1f   = (f16*)alloc((size_t)262144 * 2);
  f16* attninf = (f16*)alloc((size_t)65536 * 2);
  f16* attnoutf= (f16*)alloc((size_t)65536 * 2);
  f16* gnnwf   = (f16*)alloc((size_t)65536 * 2);
  f16* gatewf  = (f16*)alloc((size_t)131072 * 2);
  float* bias0 = (float*)alloc(1024 * 4);
  float* bias1 = (float*)alloc(1024 * 4);
  float* EW    = (float*)alloc(9216 * 4);
  float* EB    = (float*)alloc(9216 * 4);
  float* cbuf  = (float*)alloc((size_t)64 * 256 * 16 * 4);  // 1 MB c-state
  // wb: live through layer-0 windows only
  float* wb    = (float*)alloc((size_t)B_ * T_ * 18 * 4);   // 9.44 MB
  size_t off_xp = off;
  f16* xpw     = (f16*)(wsb + off_xp);                      // 134 MB window
  // tail buffers (post-scan only) alias wb onward
  size_t off2 = (size_t)((char*)wb - wsb);
  auto alloc2 = [&](size_t bytes) -> void* {
    void* p = wsb + off2;
    off2 += (bytes + 255) & ~(size_t)255;
    return p;
  };
  float* qbuf  = (float*)alloc2((size_t)B_ * 256 * 4);
  float* qk    = (float*)alloc2((size_t)B_ * 4 * 256 * 4);
  float* hbar  = (float*)alloc2((size_t)B_ * 4 * 256 * 4);
  f16* aob     = (f16*)alloc2((size_t)B_ * 256 * 2);
  float* hidden32 = (float*)alloc2((size_t)B_ * 256 * 4);
  f16* hidcat  = (f16*)alloc2((size_t)B_ * 512 * 2);
  f16* hT      = (f16*)alloc2((size_t)256 * B_ * 2);
  f16* adjn    = (f16*)alloc2((size_t)B_ * B_ * 2);
  f16* aggf    = (f16*)alloc2((size_t)B_ * 256 * 2);
  float* gnnpre= (float*)alloc2((size_t)B_ * 256 * 4);
  float* enr32 = (float*)alloc2((size_t)B_ * 256 * 4);
  float* gatepre=(float*)alloc2((size_t)B_ * 256 * 4);

  prep_kernel<<<4360, 256, 0, stream>>>(
      Whh0, Whh1, Wih1, bih0, bhh0, bih1, bhh1,
      attn_in_w, attn_out_w, gnn_w, gate_w,
      wpkR0, wpkL0, wpkR1, wpkL1, wih1f,
      attninf, attnoutf, gnnwf, gatewf, bias0, bias1);
  ew_kernel<<<36, 256, 0, stream>>>(vsn_emb_w, vsn_emb_b, Wih0, EW, EB);
  vsn_w_kernel<<<512, 256, 0, stream>>>(x, vsn_sel_w, vsn_sel_b, wb);

  // LSTM layer 0: per time-window, xp0 (Wih0 folded through VSN) -> scan
  for (int t0 = 0; t0 < T_; t0 += TW_) {
    vsn_xp_kernel<<<dim3(B_, 4), 256, 0, stream>>>(wb, EW, EB, bias0, xpw, t0);
    lstm_scan<<<64, 256, 0, stream>>>(xpw, hsbuf, wpkR0, wpkL0, cbuf, t0);
  }
  // LSTM layer 1: per window, xp1 = h0 @ Wih1^T + bias (segmented rows) -> scan
  for (int t0 = 0; t0 < T_; t0 += TW_) {
    gemm_f16<<<dim3(B_ * TW_ / 128, 8), 256, 0, stream>>>(
        hsbuf + (size_t)t0 * 256, 256, 6, (size_t)T_ * 256,
        wih1f, 256, bias1, xpw, 1024, nullptr, 0, B_ * TW_, 1024, 256);
    lstm_scan<<<64, 256, 0, stream>>>(xpw, hsbuf, wpkR1, wpkL1, cbuf, t0);
  }

  // q at t=T-1
  dim3 gS(B_ / 128, 256 / 128);
  gemm_f16<<<gS, 256, 0, stream>>>(hsbuf + (size_t)(T_ - 1) * 256, T_ * 256, 30, 0,
                                   attninf, 256, attn_in_b,
                                   nullptr, 0, qbuf, 256, B_, 256, 256);
  // attention folded into h-space
  qk_kernel<<<B_, 256, 0, stream>>>(qbuf, attn_in_w, qk);
  attnpool_kernel<<<B_, 256, 0, stream>>>(hsbuf, qk, hbar);
  vproj_kernel<<<B_, 256, 0, stream>>>(hbar, attn_in_w, attn_in_b, aob);
  // hidden
  gemm_f16<<<gS, 256, 0, stream>>>(aob, 256, 30, 0, attnoutf, 256, attn_out_b,
                                   hidcat, 512, hidden32, 256, B_, 256, 256);
  // GNN
  deg_adjn_kernel<<<B_, 256, 0, stream>>>(adj, sku, adjn);
  transpose_kernel<<<B_, 256, 0, stream>>>(hidden32, hT);
  gemm_f16<<<gS, 256, 0, stream>>>(adjn, 1024, 30, 0, hT, 1024, nullptr,
                                   aggf, 256, nullptr, 0, B_, 256, 1024);
  gemm_f16<<<gS, 256, 0, stream>>>(aggf, 256, 30, 0, gnnwf, 256, gnn_b,
                                   nullptr, 0, gnnpre, 256, B_, 256, 256);
  gelu_ln_kernel<<<B_, 256, 0, stream>>>(gnnpre, ln_g, ln_b, enr32, hidcat);
  // gate + output
  gemm_f16<<<gS, 256, 0, stream>>>(hidcat, 512, 30, 0, gatewf, 512, gate_b,
                                   nullptr, 0, gatepre, 256, B_, 256, 512);
  final_kernel<<<B_, 256, 0, stream>>>(gatepre, enr32, hidden32, out_w, out_b, (float*)d_out);
}

// Round 11
// 3365.486 us; speedup vs baseline: 1.8271x; 1.0198x over previous
//
#include <hip/hip_runtime.h>
#include <hip/hip_fp16.h>

typedef _Float16 f16;
typedef _Float16 f16x8 __attribute__((ext_vector_type(8)));
typedef float f32x4 __attribute__((ext_vector_type(4)));

#define B_ 1024
#define T_ 128
#define F_ 9
#define H_ 256
#define P_ 2048
#define TW_ 64   // time window

// ---------------- helpers ----------------
__device__ __forceinline__ float sigf(float x) { return 1.f / (1.f + __expf(-x)); }
__device__ __forceinline__ float tanh_(float x) {
  float a = fminf(fabsf(x), 12.f);
  float e = __expf(2.f * a);
  float r = 1.f - 2.f / (e + 1.f);
  return copysignf(r, x);
}

__device__ __forceinline__ float blk_sum(float v) {
  __shared__ float sh[8];
  int lane = threadIdx.x & 63, w = threadIdx.x >> 6;
  int nw = blockDim.x >> 6;
#pragma unroll
  for (int o = 32; o > 0; o >>= 1) v += __shfl_xor(v, o, 64);
  __syncthreads();
  if (lane == 0) sh[w] = v;
  __syncthreads();
  float t = 0.f;
  for (int i = 0; i < nw; i++) t += sh[i];
  return t;
}

// ---------------- generic fp16 MFMA GEMM (segmented A rows) ----------------
// A row r lives at A + (r>>seg_shift)*seg_stride + (r&mask)*lda.
// Plain layout: seg_shift=30, seg_stride=0.
__global__ __launch_bounds__(256) void gemm_f16(
    const f16* __restrict__ A, int lda, int seg_shift, size_t seg_stride,
    const f16* __restrict__ Bt, int ldb,
    const float* __restrict__ bias,
    f16* __restrict__ o16, int ldo16,
    float* __restrict__ o32, int ldo32,
    int M, int N, int K)
{
  __shared__ __align__(16) f16 As[128][40];
  __shared__ __align__(16) f16 Bs[128][40];
  const int tid = threadIdx.x;
  const int lane = tid & 63, wave = tid >> 6;
  const int wr = (wave >> 1) * 64, wc = (wave & 1) * 64;
  const int q = lane >> 4, l15 = lane & 15;
  const int bm = blockIdx.x * 128, bn = blockIdx.y * 128;
  const int smask = (1 << seg_shift) - 1;

  f32x4 acc[4][4];
#pragma unroll
  for (int i = 0; i < 4; i++)
#pragma unroll
    for (int j = 0; j < 4; j++) acc[i][j] = (f32x4){0.f, 0.f, 0.f, 0.f};

  for (int k0 = 0; k0 < K; k0 += 32) {
#pragma unroll
    for (int c = 0; c < 2; ++c) {
      int ch = tid + c * 256;
      int row = ch >> 2, kh = (ch & 3) * 8;
      int r = bm + row;
      const f16* arow = A + (size_t)(r >> seg_shift) * seg_stride
                          + (size_t)(r & smask) * lda;
      *(f16x8*)&As[row][kh] = *(const f16x8*)&arow[k0 + kh];
      *(f16x8*)&Bs[row][kh] = *(const f16x8*)&Bt[(size_t)(bn + row) * ldb + k0 + kh];
    }
    __syncthreads();
    f16x8 af[4], bf[4];
#pragma unroll
    for (int tm = 0; tm < 4; tm++) af[tm] = *(const f16x8*)&As[wr + tm * 16 + l15][q * 8];
#pragma unroll
    for (int tn = 0; tn < 4; tn++) bf[tn] = *(const f16x8*)&Bs[wc + tn * 16 + l15][q * 8];
#pragma unroll
    for (int tm = 0; tm < 4; tm++)
#pragma unroll
      for (int tn = 0; tn < 4; tn++)
        acc[tm][tn] = __builtin_amdgcn_mfma_f32_16x16x32_f16(af[tm], bf[tn], acc[tm][tn], 0, 0, 0);
    __syncthreads();
  }
#pragma unroll
  for (int tm = 0; tm < 4; tm++) {
#pragma unroll
    for (int tn = 0; tn < 4; tn++) {
      int colg = bn + wc + tn * 16 + l15;
      float bv = bias ? bias[colg] : 0.f;
#pragma unroll
      for (int r = 0; r < 4; r++) {
        int rowg = bm + wr + tm * 16 + q * 4 + r;
        float v = acc[tm][tn][r] + bv;
        if (o32) o32[(size_t)rowg * ldo32 + colg] = v;
        if (o16) o16[(size_t)rowg * ldo16 + colg] = (f16)v;
      }
    }
  }
}

// ---------------- LSTM scan: low-pressure edition ----------------
// grid 64 x 256 (4 waves, 1 wave/SIMD). Window [t0, t0+TW_).
// Gates i,f in registers (bf, 256 regs -> AGPR); gates g,o streamed from L2
// per ct, latency hidden behind the register-gate MFMAs. Single-buffer LDS,
// 2 barriers/step, NO register prefetch arrays -> arch VGPR ~190, no spill.
__global__ __launch_bounds__(256, 1) void lstm_scan(
    const f16* __restrict__ xp,    // (B, TW_, 1024), bias folded in
    f16* __restrict__ hs,          // (B, T_, 256)
    const f16* __restrict__ wpkR,  // [w4][g2][ct4][k8][lane64][8]  gates i,f
    const f16* __restrict__ wpkL,  // [w4][g2][ct4][k8][lane64][8]  gates g,o
    float* __restrict__ cbuf,      // 64*256*16 f32
    int t0)
{
  __shared__ __align__(16) f16 aph[8][64][8];     // h fragments, 8 KB
  __shared__ __align__(16) f16 xps[16 * 1032];    // 33 KB
  const int tid = threadIdx.x;
  const int lane = tid & 63, w = tid >> 6;
  const int q = lane >> 4, l15 = lane & 15;
  const int m0 = blockIdx.x * 16;

  // register gates i,f: 64 x f16x8 = 256 regs/lane (AGPR)
  f16x8 bf[2][4][8];
  {
    const f16* wr = wpkR + (size_t)w * 32768 + (size_t)lane * 8;
#pragma unroll
    for (int g = 0; g < 2; g++)
#pragma unroll
      for (int ct = 0; ct < 4; ct++)
#pragma unroll
        for (int k = 0; k < 8; k++)
          bf[g][ct][k] = *(const f16x8*)(wr + (size_t)((g * 4 + ct) * 8 + k) * 512);
  }
  const f16* wl = wpkL + (size_t)w * 32768 + (size_t)lane * 8;

  // init h fragments (zero at t0==0, else reload h[t0-1] from hs)
#pragma unroll
  for (int c = 0; c < 2; c++) {
    int sl = tid + c * 256, k = sl >> 6, ls = sl & 63;
    f16x8 h0 = {};
    if (t0 > 0)
      h0 = *(const f16x8*)&hs[((size_t)(m0 + (ls & 15)) * T_ + t0 - 1) * 256
                              + k * 32 + (ls >> 4) * 8];
    *(f16x8*)&aph[k][ls][0] = h0;
  }
  // init c-state
  float cst[4][4];
  float* cslot = cbuf + ((size_t)blockIdx.x * 256 + tid) * 16;
#pragma unroll
  for (int i = 0; i < 16; i++) cst[i >> 2][i & 3] = 0.f;
  if (t0 > 0)
#pragma unroll
    for (int i = 0; i < 16; i++) cst[i >> 2][i & 3] = cslot[i];
  // stage xp(tw=0)
#pragma unroll
  for (int c = 0; c < 8; c++) {
    int ch = tid + c * 256, row = ch >> 7, jc = (ch & 127) * 8;
    *(f16x8*)&xps[row * 1032 + jc] =
        *(const f16x8*)&xp[((size_t)(m0 + row) * TW_) * 1024 + jc];
  }
  __syncthreads();   // S1(0)

  for (int tw = 0; tw < TW_; ++tw) {
    f16 hn[4][4];
#pragma unroll
    for (int ct = 0; ct < 4; ct++) {
      // issue streamed-gate loads (L2-hot, same addrs every step)
      f16x8 bs2[8], bs3[8];
#pragma unroll
      for (int k = 0; k < 8; k++) {
        bs2[k] = *(const f16x8*)(wl + (size_t)((0 * 4 + ct) * 8 + k) * 512);
        bs3[k] = *(const f16x8*)(wl + (size_t)((1 * 4 + ct) * 8 + k) * 512);
      }
      // register-gate MFMAs first: ~310 cyc hides the ~250-cyc L2 latency
      f16x8 afk[8];
      f32x4 a0 = {0.f,0.f,0.f,0.f}, a1 = a0, a2 = a0, a3 = a0;
#pragma unroll
      for (int k = 0; k < 8; k++) {
        afk[k] = *(const f16x8*)&aph[k][lane][0];
        a0 = __builtin_amdgcn_mfma_f32_16x16x32_f16(afk[k], bf[0][ct][k], a0, 0, 0, 0);
        a1 = __builtin_amdgcn_mfma_f32_16x16x32_f16(afk[k], bf[1][ct][k], a1, 0, 0, 0);
      }
#pragma unroll
      for (int k = 0; k < 8; k++) {
        a2 = __builtin_amdgcn_mfma_f32_16x16x32_f16(afk[k], bs2[k], a2, 0, 0, 0);
        a3 = __builtin_amdgcn_mfma_f32_16x16x32_f16(afk[k], bs3[k], a3, 0, 0, 0);
      }
      int colL = w * 64 + ct * 16 + l15;
#pragma unroll
      for (int r = 0; r < 4; r++) {
        int row = q * 4 + r;
        float ip = a0[r] + (float)xps[row * 1032 + colL];
        float fp = a1[r] + (float)xps[row * 1032 + 256 + colL];
        float gp = a2[r] + (float)xps[row * 1032 + 512 + colL];
        float op = a3[r] + (float)xps[row * 1032 + 768 + colL];
        float cn = sigf(fp) * cst[ct][r] + sigf(ip) * tanh_(gp);
        cst[ct][r] = cn;
        hn[ct][r] = (f16)(sigf(op) * tanh_(cn));
      }
    }
    __syncthreads();   // S2: all aph/xps reads of step tw done
    // h_t -> LDS fragments + global hs (fire-forget)
#pragma unroll
    for (int ct = 0; ct < 4; ct++) {
      int col = w * 64 + ct * 16 + l15;
      int kh = col >> 5, ph = ((col >> 3) & 3) * 16, jh = col & 7;
#pragma unroll
      for (int r = 0; r < 4; r++) {
        int row = q * 4 + r;
        aph[kh][ph + row][jh] = hn[ct][r];
        hs[((size_t)(m0 + row) * T_ + t0 + tw) * 256 + col] = hn[ct][r];
      }
    }
    // stage xp(tw+1) straight to LDS
    if (tw + 1 < TW_) {
#pragma unroll
      for (int c = 0; c < 8; c++) {
        int ch = tid + c * 256, row = ch >> 7, jc = (ch & 127) * 8;
        *(f16x8*)&xps[row * 1032 + jc] =
            *(const f16x8*)&xp[((size_t)(m0 + row) * TW_ + tw + 1) * 1024 + jc];
      }
    }
    __syncthreads();   // S1(tw+1)
  }
#pragma unroll
  for (int i = 0; i < 16; i++) cslot[i] = cst[i >> 2][i & 3];
}

// ---------------- VSN phase 1: softmax weights ----------------
__global__ __launch_bounds__(256) void vsn_w_kernel(
    const float* __restrict__ x, const float* __restrict__ selw,
    const float* __restrict__ selb, float* __restrict__ wb)
{
  int pos = blockIdx.x * 256 + threadIdx.x;
  const float* xr = x + (size_t)pos * F_;
  float xv[F_];
#pragma unroll
  for (int f = 0; f < F_; f++) xv[f] = xr[f];
  float wv[F_]; float mx = -1e30f;
#pragma unroll
  for (int f = 0; f < F_; f++) {
    float s = selb[f];
#pragma unroll
    for (int f2 = 0; f2 < F_; f2++) s += xv[f2] * selw[f * F_ + f2];
    wv[f] = s; mx = fmaxf(mx, s);
  }
  float se = 0.f;
#pragma unroll
  for (int f = 0; f < F_; f++) { wv[f] = __expf(wv[f] - mx); se += wv[f]; }
  float inv = 1.f / se;
  float* o = wb + (size_t)pos * 18;
#pragma unroll
  for (int f = 0; f < F_; f++) {
    float wt = wv[f] * inv;
    o[f] = wt; o[9 + f] = wt * xv[f];
  }
}

// ---------------- EW/EB: fold Wih0 through the VSN basis ----------------
__global__ __launch_bounds__(256) void ew_kernel(
    const float* __restrict__ embw, const float* __restrict__ embb,
    const float* __restrict__ Wih0, float* __restrict__ EW, float* __restrict__ EB)
{
  int idx = blockIdx.x * 256 + threadIdx.x;   // 36 blocks
  int f = idx >> 10, j = idx & 1023;
  const float* er = embw + f * H_;
  const float* br = embb + f * H_;
  const float* wr = Wih0 + (size_t)j * H_;
  float ew = 0.f, eb = 0.f;
  for (int k = 0; k < H_; k++) { ew += er[k] * wr[k]; eb += br[k] * wr[k]; }
  EW[idx] = ew; EB[idx] = eb;
}

// ---------------- xp0 window = VSN folded through Wih0 ----------------
__global__ __launch_bounds__(256) void vsn_xp_kernel(
    const float* __restrict__ wb, const float* __restrict__ EW,
    const float* __restrict__ EB, const float* __restrict__ bias0,
    f16* __restrict__ xp, int t0)
{
  int col = blockIdx.y * 256 + threadIdx.x;
  float ew[F_], eb[F_];
#pragma unroll
  for (int f = 0; f < F_; f++) { ew[f] = EW[f * 1024 + col]; eb[f] = EB[f * 1024 + col]; }
  float b0 = bias0[col];
  int r = blockIdx.x;
  for (int t = 0; t < TW_; t++) {
    const float* wv = wb + ((size_t)r * T_ + t0 + t) * 18;
    float v = b0;
#pragma unroll
    for (int f = 0; f < F_; f++) v += wv[9 + f] * ew[f] + wv[f] * eb[f];
    xp[((size_t)r * TW_ + t) * 1024 + col] = (f16)v;
  }
}

// ---------------- attention in h-space ----------------
__global__ __launch_bounds__(256) void qk_kernel(
    const float* __restrict__ qbuf, const float* __restrict__ attn_in_w,
    float* __restrict__ qk)
{
  __shared__ float qs[256];
  int b = blockIdx.x, j = threadIdx.x;
  qs[j] = qbuf[(size_t)b * 256 + j];
  __syncthreads();
#pragma unroll
  for (int h = 0; h < 4; h++) {
    float acc = 0.f;
    for (int d = 0; d < 64; d++)
      acc += qs[h * 64 + d] * attn_in_w[(size_t)(256 + h * 64 + d) * 256 + j];
    qk[((size_t)b * 4 + h) * 256 + j] = acc * 0.125f;
  }
}

__global__ __launch_bounds__(256) void attnpool_kernel(
    const f16* __restrict__ hseq, const float* __restrict__ qk,
    float* __restrict__ hbar)
{
  __shared__ __align__(16) f16 hsb[T_][264];
  __shared__ float qks[4][256];
  __shared__ float ps[4][T_];
  int b = blockIdx.x, tid = threadIdx.x;
  for (int i = tid; i < T_ * 32; i += 256) {
    int row = i >> 5, cc = (i & 31) * 8;
    *(f16x8*)&hsb[row][cc] = *(const f16x8*)&hseq[((size_t)b * T_ + row) * 256 + cc];
  }
  for (int i = tid; i < 1024; i += 256) qks[i >> 8][i & 255] = qk[(size_t)b * 1024 + i];
  __syncthreads();
  if (tid < T_) {
    float s[4] = {0.f, 0.f, 0.f, 0.f};
    for (int cc = 0; cc < 32; cc++) {
      f16x8 v = *(const f16x8*)&hsb[tid][cc * 8];
#pragma unroll
      for (int h = 0; h < 4; h++) {
        float a = 0.f;
#pragma unroll
        for (int j = 0; j < 8; j++) a += qks[h][cc * 8 + j] * (float)v[j];
        s[h] += a;
      }
    }
#pragma unroll
    for (int h = 0; h < 4; h++) ps[h][tid] = s[h];
  }
  __syncthreads();
  {
    int w = tid >> 6, l = tid & 63;
    float a = ps[w][l], bb = ps[w][l + 64];
    float m = fmaxf(a, bb);
#pragma unroll
    for (int o = 32; o > 0; o >>= 1) m = fmaxf(m, __shfl_xor(m, o, 64));
    float e0 = __expf(a - m), e1 = __expf(bb - m);
    float se = e0 + e1;
#pragma unroll
    for (int o = 32; o > 0; o >>= 1) se += __shfl_xor(se, o, 64);
    float inv = 1.f / se;
    ps[w][l] = e0 * inv; ps[w][l + 64] = e1 * inv;
  }
  __syncthreads();
  int j = tid;
  float acc[4] = {0.f, 0.f, 0.f, 0.f};
  for (int t = 0; t < T_; t++) {
    float hv = (float)hsb[t][j];
#pragma unroll
    for (int h = 0; h < 4; h++) acc[h] += ps[h][t] * hv;
  }
#pragma unroll
  for (int h = 0; h < 4; h++) hbar[((size_t)b * 4 + h) * 256 + j] = acc[h];
}

__global__ __launch_bounds__(256) void vproj_kernel(
    const float* __restrict__ hbar, const float* __restrict__ attn_in_w,
    const float* __restrict__ attn_in_b, f16* __restrict__ aob)
{
  __shared__ float hb[4][256];
  int b = blockIdx.x, tid = threadIdx.x;
  for (int i = tid; i < 1024; i += 256) hb[i >> 8][i & 255] = hbar[(size_t)b * 1024 + i];
  __syncthreads();
  int d = tid, h = d >> 6;
  const float4* wr = (const float4*)(attn_in_w + (size_t)(512 + d) * 256);
  float acc = 0.f;
  for (int cc = 0; cc < 64; cc++) {
    float4 w4 = wr[cc];
    acc += w4.x * hb[h][cc * 4] + w4.y * hb[h][cc * 4 + 1]
         + w4.z * hb[h][cc * 4 + 2] + w4.w * hb[h][cc * 4 + 3];
  }
  aob[(size_t)b * 256 + d] = (f16)(acc + attn_in_b[512 + d]);
}

// ---------------- GNN prep ----------------
__global__ __launch_bounds__(256) void deg_adjn_kernel(
    const float* __restrict__ adj, const int* __restrict__ sku,
    f16* __restrict__ adjn)
{
  int bp = blockIdx.x;
  int p = sku[bp];
  int tid = threadIdx.x;
  float s = 0.f;
  for (int j = tid; j < P_; j += 256) s += adj[(size_t)p * P_ + j];
  float tot = blk_sum(s);
  float inv = 1.f / fmaxf(tot, 1e-6f);
  for (int b = tid; b < B_; b += 256)
    adjn[(size_t)bp * B_ + b] = (f16)(adj[(size_t)p * P_ + sku[b]] * inv);
}

__global__ void transpose_kernel(const float* __restrict__ hid, f16* __restrict__ hT)
{
  int i = blockIdx.x * 256 + threadIdx.x;
  int b = i >> 8, j = i & 255;
  hT[(size_t)j * B_ + b] = (f16)hid[i];
}

__global__ __launch_bounds__(256) void gelu_ln_kernel(
    const float* __restrict__ pre, const float* __restrict__ lg,
    const float* __restrict__ lb, float* __restrict__ enr,
    f16* __restrict__ hidcat)
{
  int row = blockIdx.x, j = threadIdx.x;
  float xv = pre[row * 256 + j];
  float ge = 0.5f * xv * (1.f + erff(xv * 0.70710678118654752f));
  float mu = blk_sum(ge) * (1.f / 256.f);
  float d = ge - mu;
  float var = blk_sum(d * d) * (1.f / 256.f);
  float y = d * rsqrtf(var + 1e-5f) * lg[j] + lb[j];
  enr[row * 256 + j] = y;
  hidcat[row * 512 + 256 + j] = (f16)y;
}

__global__ __launch_bounds__(256) void final_kernel(
    const float* __restrict__ gpre, const float* __restrict__ enr,
    const float* __restrict__ hid, const float* __restrict__ outw,
    const float* __restrict__ outb, float* __restrict__ out)
{
  int b = blockIdx.x, j = threadIdx.x;
  float gt = sigf(gpre[b * 256 + j]);
  float comb = gt * enr[b * 256 + j] + (1.f - gt) * hid[b * 256 + j];
  float v = comb * outw[j];
  float s = blk_sum(v);
  if (j == 0) out[b] = s + outb[0];
}

// ---------------- one-shot weight prep ----------------
// Whh pack per layer (262144): R half (gates i,f): [w4][g2][ct4][k8][lane64][j8]
//   row = g*256 + w*64 + ct*16 + (lane&15); col = k*32 + (lane>>4)*8 + j
// L half (gates g,o): same layout, row = (2+g)*256 + w*64 + ct*16 + (lane&15)
// Segments: 524288 + 262144 + 65536*3 + 131072 + 2*1024 = 1116160 = 4360 blocks.
__global__ void prep_kernel(
    const float* Whh0, const float* Whh1, const float* Wih1,
    const float* bih0, const float* bhh0, const float* bih1, const float* bhh1,
    const float* attn_in_w, const float* attn_out_w, const float* gnn_w,
    const float* gate_w,
    f16* wpkR0, f16* wpkL0, f16* wpkR1, f16* wpkL1, f16* wih1f,
    f16* attninf, f16* attnoutf, f16* gnnwf, f16* gatewf,
    float* bias0, float* bias1)
{
  int idx = blockIdx.x * 256 + threadIdx.x;
  if (idx < 524288) {
    int l = idx >> 18;
    int i = idx & 262143;
    const float* Whh = l ? Whh1 : Whh0;
    int half = (i >= 131072);
    int ih = i & 131071;
    int w = ih >> 15, r1 = ih & 32767;
    int g = r1 >> 14, r2 = r1 & 16383;
    int ct = r2 >> 12, k = (r2 >> 9) & 7, lane = (r2 >> 3) & 63, j = r2 & 7;
    int row = (half * 2 + g) * 256 + w * 64 + ct * 16 + (lane & 15);
    int col = k * 32 + (lane >> 4) * 8 + j;
    f16 v = (f16)Whh[(size_t)row * 256 + col];
    if (l) { if (half) wpkL1[ih] = v; else wpkR1[ih] = v; }
    else   { if (half) wpkL0[ih] = v; else wpkR0[ih] = v; }
    return;
  }
  int i = idx - 524288;
  if (i < 262144) { wih1f[i] = (f16)Wih1[i]; return; }
  i -= 262144;
  if (i < 65536) { attninf[i] = (f16)attn_in_w[i]; return; }
  i -= 65536;
  if (i < 65536) { attnoutf[i] = (f16)attn_out_w[i]; return; }
  i -= 65536;
  if (i < 65536) { gnnwf[i] = (f16)gnn_w[i]; return; }
  i -= 65536;
  if (i < 131072) { gatewf[i] = (f16)gate_w[i]; return; }
  i -= 131072;
  if (i < 1024) { bias0[i] = bih0[i] + bhh0[i]; return; }
  i -= 1024;
  if (i < 1024) { bias1[i] = bih1[i] + bhh1[i]; return; }
}

// ---------------- launch ----------------
extern "C" void kernel_launch(void* const* d_in, const int* in_sizes, int n_in,
                              void* d_out, int out_size, void* d_ws, size_t ws_size,
                              hipStream_t stream)
{
  const float* x         = (const float*)d_in[0];
  const int*   sku       = (const int*)  d_in[1];
  const float* adj       = (const float*)d_in[2];
  const float* vsn_emb_w = (const float*)d_in[3];
  const float* vsn_emb_b = (const float*)d_in[4];
  const float* vsn_sel_w = (const float*)d_in[5];
  const float* vsn_sel_b = (const float*)d_in[6];
  const float* Wih0 = (const float*)d_in[7];
  const float* Whh0 = (const float*)d_in[8];
  const float* bih0 = (const float*)d_in[9];
  const float* bhh0 = (const float*)d_in[10];
  const float* Wih1 = (const float*)d_in[11];
  const float* Whh1 = (const float*)d_in[12];
  const float* bih1 = (const float*)d_in[13];
  const float* bhh1 = (const float*)d_in[14];
  const float* attn_in_w  = (const float*)d_in[15];
  const float* attn_in_b  = (const float*)d_in[16];
  const float* attn_out_w = (const float*)d_in[17];
  const float* attn_out_b = (const float*)d_in[18];
  const float* gnn_w  = (const float*)d_in[19];
  const float* gnn_b  = (const float*)d_in[20];
  const float* ln_g   = (const float*)d_in[21];
  const float* ln_b   = (const float*)d_in[22];
  const float* gate_w = (const float*)d_in[23];
  const float* gate_b = (const float*)d_in[24];
  const float* out_w  = (const float*)d_in[25];
  const float* out_b  = (const float*)d_in[26];
  (void)in_sizes; (void)n_in; (void)out_size; (void)ws_size;

  char* wsb = (char*)d_ws;
  size_t off = 0;
  auto alloc = [&](size_t bytes) -> void* {
    void* p = wsb + off;
    off += (bytes + 255) & ~(size_t)255;
    return p;
  };
  // persistent region (~80 MB)
  f16* hsbuf   = (f16*)alloc((size_t)B_ * T_ * H_ * 2);    // 67 MB
  f16* wpkR0   = (f16*)alloc((size_t)131072 * 2);
  f16* wpkL0   = (f16*)alloc((size_t)131072 * 2);
  f16* wpkR1   = (f16*)alloc((size_t)131072 * 2);
  f16* wpkL1   = (f16*)alloc((size_t)131072 * 2);
  f16* wih1f   = (f16*)alloc((size_t)262144 * 2);
  f16* attninf = (f16*)alloc((size_t)65536 * 2);
  f16* attnoutf= (f16*)alloc((size_t)65536 * 2);
  f16* gnnwf   = (f16*)alloc((size_t)65536 * 2);
  f16* gatewf  = (f16*)alloc((size_t)131072 * 2);
  float* bias0 = (float*)alloc(1024 * 4);
  float* bias1 = (float*)alloc(1024 * 4);
  float* EW    = (float*)alloc(9216 * 4);
  float* EB    = (float*)alloc(9216 * 4);
  float* cbuf  = (float*)alloc((size_t)64 * 256 * 16 * 4);  // 1 MB c-state
  // wb: live through layer-0 windows only
  float* wb    = (float*)alloc((size_t)B_ * T_ * 18 * 4);   // 9.44 MB
  size_t off_xp = off;
  f16* xpw     = (f16*)(wsb + off_xp);                      // 134 MB window
  // tail buffers (post-scan only) alias wb onward
  size_t off2 = (size_t)((char*)wb - wsb);
  auto alloc2 = [&](size_t bytes) -> void* {
    void* p = wsb + off2;
    off2 += (bytes + 255) & ~(size_t)255;
    return p;
  };
  float* qbuf  = (float*)alloc2((size_t)B_ * 256 * 4);
  float* qk    = (float*)alloc2((size_t)B_ * 4 * 256 * 4);
  float* hbar  = (float*)alloc2((size_t)B_ * 4 * 256 * 4);
  f16* aob     = (f16*)alloc2((size_t)B_ * 256 * 2);
  float* hidden32 = (float*)alloc2((size_t)B_ * 256 * 4);
  f16* hidcat  = (f16*)alloc2((size_t)B_ * 512 * 2);
  f16* hT      = (f16*)alloc2((size_t)256 * B_ * 2);
  f16* adjn    = (f16*)alloc2((size_t)B_ * B_ * 2);
  f16* aggf    = (f16*)alloc2((size_t)B_ * 256 * 2);
  float* gnnpre= (float*)alloc2((size_t)B_ * 256 * 4);
  float* enr32 = (float*)alloc2((size_t)B_ * 256 * 4);
  float* gatepre=(float*)alloc2((size_t)B_ * 256 * 4);

  prep_kernel<<<4360, 256, 0, stream>>>(
      Whh0, Whh1, Wih1, bih0, bhh0, bih1, bhh1,
      attn_in_w, attn_out_w, gnn_w, gate_w,
      wpkR0, wpkL0, wpkR1, wpkL1, wih1f,
      attninf, attnoutf, gnnwf, gatewf, bias0, bias1);
  ew_kernel<<<36, 256, 0, stream>>>(vsn_emb_w, vsn_emb_b, Wih0, EW, EB);
  vsn_w_kernel<<<512, 256, 0, stream>>>(x, vsn_sel_w, vsn_sel_b, wb);

  // LSTM layer 0: per time-window, xp0 (Wih0 folded through VSN) -> scan
  for (int t0 = 0; t0 < T_; t0 += TW_) {
    vsn_xp_kernel<<<dim3(B_, 4), 256, 0, stream>>>(wb, EW, EB, bias0, xpw, t0);
    lstm_scan<<<64, 256, 0, stream>>>(xpw, hsbuf, wpkR0, wpkL0, cbuf, t0);
  }
  // LSTM layer 1: per window, xp1 = h0 @ Wih1^T + bias (segmented rows) -> scan
  for (int t0 = 0; t0 < T_; t0 += TW_) {
    gemm_f16<<<dim3(B_ * TW_ / 128, 8), 256, 0, stream>>>(
        hsbuf + (size_t)t0 * 256, 256, 6, (size_t)T_ * 256,
        wih1f, 256, bias1, xpw, 1024, nullptr, 0, B_ * TW_, 1024, 256);
    lstm_scan<<<64, 256, 0, stream>>>(xpw, hsbuf, wpkR1, wpkL1, cbuf, t0);
  }

  // q at t=T-1
  dim3 gS(B_ / 128, 256 / 128);
  gemm_f16<<<gS, 256, 0, stream>>>(hsbuf + (size_t)(T_ - 1) * 256, T_ * 256, 30, 0,
                                   attninf, 256, attn_in_b,
                                   nullptr, 0, qbuf, 256, B_, 256, 256);
  // attention folded into h-space
  qk_kernel<<<B_, 256, 0, stream>>>(qbuf, attn_in_w, qk);
  attnpool_kernel<<<B_, 256, 0, stream>>>(hsbuf, qk, hbar);
  vproj_kernel<<<B_, 256, 0, stream>>>(hbar, attn_in_w, attn_in_b, aob);
  // hidden
  gemm_f16<<<gS, 256, 0, stream>>>(aob, 256, 30, 0, attnoutf, 256, attn_out_b,
                                   hidcat, 512, hidden32, 256, B_, 256, 256);
  // GNN
  deg_adjn_kernel<<<B_, 256, 0, stream>>>(adj, sku, adjn);
  transpose_kernel<<<B_, 256, 0, stream>>>(hidden32, hT);
  gemm_f16<<<gS, 256, 0, stream>>>(adjn, 1024, 30, 0, hT, 1024, nullptr,
                                   aggf, 256, nullptr, 0, B_, 256, 1024);
  gemm_f16<<<gS, 256, 0, stream>>>(aggf, 256, 30, 0, gnnwf, 256, gnn_b,
                                   nullptr, 0, gnnpre, 256, B_, 256, 256);
  gelu_ln_kernel<<<B_, 256, 0, stream>>>(gnnpre, ln_g, ln_b, enr32, hidcat);
  // gate + output
  gemm_f16<<<gS, 256, 0, stream>>>(hidcat, 512, 30, 0, gatewf, 512, gate_b,
                                   nullptr, 0, gatepre, 256, B_, 256, 512);
  final_kernel<<<B_, 256, 0, stream>>>(gatepre, enr32, hidden32, out_w, out_b, (float*)d_out);
}